// Round 14
// baseline (419.260 us; speedup 1.0000x reference)
//
#include <hip/hip_runtime.h>
#include <math.h>

#define BQ 4
#define DM 192
#define DI 384
#define HH 48
#define WW 48
#define LL 2304
#define KK 4
#define NN 16
#define RR 12
#define CH 48      // chunks per sequence
#define CLEN 48    // chunk length

#define LOG2E 1.4426950408889634f

typedef short v8s __attribute__((ext_vector_type(8)));
typedef float v4f __attribute__((ext_vector_type(4)));

__device__ __forceinline__ float gelu_exact(float x) {
    return 0.5f * x * (1.0f + erff(x * 0.7071067811865476f));
}

__device__ __forceinline__ float softplus_f(float x) {
    return fmaxf(x, 0.0f) + log1pf(expf(-fabsf(x)));
}

__device__ __forceinline__ int pos_for(int k, int l) {
    if (k == 0) return l;
    if (k == 1) { return (l % HH) * WW + (l / HH); }
    if (k == 2) return (LL - 1) - l;
    int j = (LL - 1) - l;
    return (j % HH) * WW + (j / HH);
}

__device__ __forceinline__ int pt_of(int p) {   // 48x48 transpose, involution
    return (p % 48) * 48 + p / 48;
}

__device__ __forceinline__ float fexp2(float x) {
    return __builtin_amdgcn_exp2f(x);
}

__device__ __forceinline__ short f2bf(float x) {
    unsigned u = __float_as_uint(x);
    unsigned r = (u + 0x7FFFu + ((u >> 16) & 1u)) >> 16;
    return (short)r;
}

// DPP move: 0x00-0xFF quad_perm; 0xB1 = quad xor1, 0x4E = quad xor2.
template<int CTRL>
__device__ __forceinline__ float dpp_movf(float v) {
    return __int_as_float(__builtin_amdgcn_update_dpp(
        0, __float_as_int(v), CTRL, 0xF, 0xF, true));
}

// ---------------- P1: cast weights to bf16. wpbf = x_proj (176,384) padded to 192 rows.
__global__ __launch_bounds__(256) void k_prep_w(const float* __restrict__ ipw,
                                                const float* __restrict__ opw,
                                                const float* __restrict__ xpw,
                                                short* __restrict__ wibf,
                                                short* __restrict__ owbf,
                                                short* __restrict__ wpbf) {
    int i = blockIdx.x * 256 + threadIdx.x;     // 1152*256 = 294912 exactly
    if (i < 147456)       wibf[i] = f2bf(ipw[i]);
    else if (i < 221184)  owbf[i - 147456] = f2bf(opw[i - 147456]);
    else if (i < 288768)  wpbf[i - 221184] = f2bf(xpw[i - 221184]);
    else                  wpbf[67584 + (i - 288768)] = 0;   // pad rows 176..191
}

// ---------------- P2: transpose-cast x (B,192,L) -> xTbf (B,L,192) bf16
__global__ __launch_bounds__(256) void k_prep_xT(const float* __restrict__ x,
                                                 short* __restrict__ xTbf) {
    __shared__ float T[32][33];
    int blk = blockIdx.x;           // (b*72 + lt)*6 + dt
    int dt = blk % 6;
    int lt = (blk / 6) % 72;
    int b  = blk / (6 * 72);
    int d0 = dt * 32, l0 = lt * 32;
    int tx = threadIdx.x & 31, ty = threadIdx.x >> 5;   // ty 0..7
    #pragma unroll
    for (int i = 0; i < 4; ++i) {
        int dd = ty + 8 * i;
        T[dd][tx] = x[(size_t)(b * DM + d0 + dd) * LL + l0 + tx];
    }
    __syncthreads();
    #pragma unroll
    for (int i = 0; i < 4; ++i) {
        int ll = ty + 8 * i;
        xTbf[(size_t)(b * LL + l0 + ll) * DM + d0 + tx] = f2bf(T[tx][ll]);
    }
}

// ---------------- K1: in_proj via bf16 MFMA. D[l][o]; o<384 -> xc, else gelu->z.
__global__ __launch_bounds__(256) void k_inproj_mfma(
    const short* __restrict__ xTbf,   // (B,L,192) bf16
    const short* __restrict__ wibf,   // (768,192) bf16
    float* __restrict__ xcz)          // (B,L,768) fp32
{
    __shared__ short sA[128 * 40];    // [l][k32], row stride 40 shorts
    __shared__ short sB[64 * 40];     // [o][k32]
    int o0 = blockIdx.x * 64;
    int l0 = blockIdx.y * 128;
    int b  = blockIdx.z;
    int tid = threadIdx.x;
    int lane = tid & 63, wid = tid >> 6;
    int n = lane & 15, quad = lane >> 4;

    v4f acc[2][4];
    #pragma unroll
    for (int i = 0; i < 2; ++i)
        #pragma unroll
        for (int j = 0; j < 4; ++j) acc[i][j] = (v4f){0.f, 0.f, 0.f, 0.f};

    for (int kc = 0; kc < 192; kc += 32) {
        for (int i = tid; i < 512; i += 256) {
            int row = i >> 2, seg = i & 3;
            *(v8s*)&sA[row * 40 + seg * 8] =
                *(const v8s*)(xTbf + (size_t)(b * LL + l0 + row) * DM + kc + seg * 8);
        }
        {
            int row = tid >> 2, seg = tid & 3;
            *(v8s*)&sB[row * 40 + seg * 8] =
                *(const v8s*)(wibf + (size_t)(o0 + row) * DM + kc + seg * 8);
        }
        __syncthreads();
        v8s a0 = *(v8s*)&sA[(wid * 32 + n) * 40 + quad * 8];
        v8s a1 = *(v8s*)&sA[(wid * 32 + 16 + n) * 40 + quad * 8];
        #pragma unroll
        for (int os = 0; os < 4; ++os) {
            v8s bv = *(v8s*)&sB[(os * 16 + n) * 40 + quad * 8];
            acc[0][os] = __builtin_amdgcn_mfma_f32_16x16x32_bf16(a0, bv, acc[0][os], 0, 0, 0);
            acc[1][os] = __builtin_amdgcn_mfma_f32_16x16x32_bf16(a1, bv, acc[1][os], 0, 0, 0);
        }
        __syncthreads();
    }
    bool zhalf = (o0 >= DI);
    #pragma unroll
    for (int ls = 0; ls < 2; ++ls)
        #pragma unroll
        for (int os = 0; os < 4; ++os) {
            int o = o0 + os * 16 + n;
            #pragma unroll
            for (int r = 0; r < 4; ++r) {
                int l = l0 + wid * 32 + ls * 16 + quad * 4 + r;
                float v = acc[ls][os][r];
                xcz[(size_t)(b * LL + l) * 768 + o] = zhalf ? gelu_exact(v) : v;
            }
        }
}

// ---------------- K2: depthwise 3x3 conv + bias + gelu, [l][c] layout.
__global__ __launch_bounds__(384) void k_dwconv(const float* __restrict__ xcz,
                                                const float* __restrict__ cw,
                                                const float* __restrict__ cb,
                                                float* __restrict__ xcT,
                                                short* __restrict__ xcTbf) {
    int blk = blockIdx.x;           // ((b*HH + h)*4 + seg)
    int seg = blk & 3;
    int bh = blk >> 2;
    int b = bh / HH, h = bh % HH;
    int d = threadIdx.x;
    int w0 = seg * 12;
    const float* in = xcz + (size_t)b * LL * 768 + d;
    float w9[9];
    #pragma unroll
    for (int i = 0; i < 9; ++i) w9[i] = cw[d * 9 + i];
    float bias = cb[d];
    bool hm = h > 0, hp = h < HH - 1;
    int r0 = (h - 1) * WW, r1 = h * WW, r2 = (h + 1) * WW;
    float c00, c01, c02, c10, c11, c12, c20, c21, c22;
    bool wl = (w0 > 0);
    c00 = (hm && wl) ? in[(size_t)(r0 + w0 - 1) * 768] : 0.f;
    c10 = wl ? in[(size_t)(r1 + w0 - 1) * 768] : 0.f;
    c20 = (hp && wl) ? in[(size_t)(r2 + w0 - 1) * 768] : 0.f;
    c01 = hm ? in[(size_t)(r0 + w0) * 768] : 0.f;
    c11 = in[(size_t)(r1 + w0) * 768];
    c21 = hp ? in[(size_t)(r2 + w0) * 768] : 0.f;
    c02 = hm ? in[(size_t)(r0 + w0 + 1) * 768] : 0.f;
    c12 = in[(size_t)(r1 + w0 + 1) * 768];
    c22 = hp ? in[(size_t)(r2 + w0 + 1) * 768] : 0.f;
    #pragma unroll
    for (int wi = 0; wi < 12; ++wi) {
        int w = w0 + wi;
        float s = bias
            + w9[0] * c00 + w9[1] * c01 + w9[2] * c02
            + w9[3] * c10 + w9[4] * c11 + w9[5] * c12
            + w9[6] * c20 + w9[7] * c21 + w9[8] * c22;
        float v = gelu_exact(s);
        size_t row = (size_t)(b * LL + h * WW + w);
        xcT[row * DI + d] = v;
        xcTbf[row * DI + d] = f2bf(v);
        c00 = c01; c01 = c02; c10 = c11; c11 = c12; c20 = c21; c21 = c22;
        int wn = w + 2;
        bool okw = wn < WW;
        c02 = (hm && okw) ? in[(size_t)(r0 + wn) * 768] : 0.f;
        c12 = okw ? in[(size_t)(r1 + wn) * 768] : 0.f;
        c22 = (hp && okw) ? in[(size_t)(r2 + wn) * 768] : 0.f;
    }
}

// ---------------- K3: x_proj, ALL 4 directions as ONE bf16 MFMA GEMM.
__global__ __launch_bounds__(256) void k_xproj_mfma(
    const short* __restrict__ xcTbf,  // (B,L,384) bf16
    const short* __restrict__ wpbf,   // (192,384) bf16, rows>=176 zero
    float* __restrict__ dts,
    float* __restrict__ Bsb,
    float* __restrict__ Csb)
{
    __shared__ short sA[128 * 40];
    __shared__ short sB[64 * 40];
    int o0 = blockIdx.x * 64;
    int l0 = blockIdx.y * 128;
    int b  = blockIdx.z;
    int tid = threadIdx.x;
    int lane = tid & 63, wid = tid >> 6;
    int n = lane & 15, quad = lane >> 4;

    v4f acc[2][4];
    #pragma unroll
    for (int i = 0; i < 2; ++i)
        #pragma unroll
        for (int j = 0; j < 4; ++j) acc[i][j] = (v4f){0.f, 0.f, 0.f, 0.f};

    for (int kc = 0; kc < DI; kc += 32) {
        for (int i = tid; i < 512; i += 256) {
            int row = i >> 2, seg = i & 3;
            *(v8s*)&sA[row * 40 + seg * 8] =
                *(const v8s*)(xcTbf + (size_t)(b * LL + l0 + row) * DI + kc + seg * 8);
        }
        {
            int row = tid >> 2, seg = tid & 3;
            *(v8s*)&sB[row * 40 + seg * 8] =
                *(const v8s*)(wpbf + (size_t)(o0 + row) * DI + kc + seg * 8);
        }
        __syncthreads();
        v8s a0 = *(v8s*)&sA[(wid * 32 + n) * 40 + quad * 8];
        v8s a1 = *(v8s*)&sA[(wid * 32 + 16 + n) * 40 + quad * 8];
        #pragma unroll
        for (int os = 0; os < 4; ++os) {
            v8s bv = *(v8s*)&sB[(os * 16 + n) * 40 + quad * 8];
            acc[0][os] = __builtin_amdgcn_mfma_f32_16x16x32_bf16(a0, bv, acc[0][os], 0, 0, 0);
            acc[1][os] = __builtin_amdgcn_mfma_f32_16x16x32_bf16(a1, bv, acc[1][os], 0, 0, 0);
        }
        __syncthreads();
    }
    #pragma unroll
    for (int ls = 0; ls < 2; ++ls)
        #pragma unroll
        for (int os = 0; os < 4; ++os) {
            int c_all = o0 + os * 16 + n;
            if (c_all >= 176) continue;
            int k = c_all / 44;
            int c = c_all - k * 44;
            int bk = b * 4 + k;
            #pragma unroll
            for (int r = 0; r < 4; ++r) {
                int lp = l0 + wid * 32 + ls * 16 + quad * 4 + r;
                int lk = (k == 0) ? lp
                       : (k == 1) ? pt_of(lp)
                       : (k == 2) ? (LL - 1 - lp)
                                  : (LL - 1 - pt_of(lp));
                float v = acc[ls][os][r];
                size_t base = (size_t)bk * LL + lk;
                if (c < RR)           dts[base * RR + c] = v;
                else if (c < RR + NN) Bsb[base * NN + (c - RR)] = v;
                else                  Csb[base * NN + (c - RR - NN)] = v;
            }
        }
}

// ---------------- Single-pass chunked scan, stage-then-scan.
// NEW (R14): 2 d's per lane — wave covers 32 d, halving the per-CU LDS-issue
// cost of the broadcast B/C reads (they were duplicated per wave). Block =
// 128 threads (2 waves) covering 64 d. Outputs identical to R11.
__global__ __launch_bounds__(128) void k_scan_pass1(
    const float* __restrict__ xcT,
    const float* __restrict__ dts,
    const float* __restrict__ Bsb,
    const float* __restrict__ Csb,
    const float* __restrict__ dtw_g,
    const float* __restrict__ dtb_g,
    const float* __restrict__ Alogs,
    const float* __restrict__ Ds_g,
    float* __restrict__ Sbuf,
    float* __restrict__ hstin,
    float* __restrict__ yk)
{
    __shared__ float sB[CLEN * 16];      // [l][n]   3 KB
    __shared__ float sC[CLEN * 16];      //          3 KB
    __shared__ float sDts[CLEN * 12];    // [l][r]   2.25 KB
    __shared__ float sDel[CLEN * 64];    // [l][dl]  12 KB
    __shared__ float sU[CLEN * 64];      // [l][dl]  12 KB

    int blk = blockIdx.x;                 // ((bk*CH + c)*6 + dblk)
    int dblk = blk % 6;
    int tmp = blk / 6;
    int c = tmp % CH;
    int bk = tmp / CH;
    int k = bk & 3, b = bk >> 2;
    int tid = threadIdx.x;                // [0,128)
    int l0 = c * CLEN;

    // ---- stage B, C (192 float4 each), dts (144 float4)
    {
        const float4* Bg = (const float4*)(Bsb + ((size_t)bk * LL + l0) * NN);
        const float4* Cg = (const float4*)(Csb + ((size_t)bk * LL + l0) * NN);
        ((float4*)sB)[tid] = Bg[tid];
        ((float4*)sC)[tid] = Cg[tid];
        int i2 = tid + 128;
        if (i2 < CLEN * 4) {
            ((float4*)sB)[i2] = Bg[i2];
            ((float4*)sC)[i2] = Cg[i2];
        }
        const float4* Dg = (const float4*)(dts + ((size_t)bk * LL + l0) * RR);
        ((float4*)sDts)[tid] = Dg[tid];           // tid < 128 < 144
        if (i2 < CLEN * 3) ((float4*)sDts)[i2] = Dg[i2];
    }
    // ---- stage u: 768 float4 over 128 threads
    {
        const float* xb = xcT + (size_t)b * LL * DI + dblk * 64;
        #pragma unroll
        for (int it = 0; it < 6; ++it) {
            int i = it * 128 + tid;
            int l = i >> 4, f4 = i & 15;
            int pos = pos_for(k, l0 + l);
            ((float4*)sU)[l * 16 + f4] = *(const float4*)(xb + (size_t)pos * DI + f4 * 4);
        }
    }
    __syncthreads();
    // ---- delta precompute: 3072 values over 128 threads (24 each)
    {
        int dl = tid & 63, lset = tid >> 6;       // lset in {0,1}
        int dd = dblk * 64 + dl;
        int kdq = k * DI + dd;
        float dtbv = dtb_g[kdq];
        float w12[12];
        {
            const float4* p = (const float4*)(dtw_g + (size_t)kdq * RR);
            float4 a0 = p[0], a1 = p[1], a2 = p[2];
            w12[0]=a0.x; w12[1]=a0.y; w12[2]=a0.z;  w12[3]=a0.w;
            w12[4]=a1.x; w12[5]=a1.y; w12[6]=a1.z;  w12[7]=a1.w;
            w12[8]=a2.x; w12[9]=a2.y; w12[10]=a2.z; w12[11]=a2.w;
        }
        #pragma unroll
        for (int j = 0; j < 24; ++j) {
            int l = lset * 24 + j;
            const float* dp = sDts + l * 12;
            float acc = dtbv;
            #pragma unroll
            for (int r = 0; r < 12; ++r) acc += dp[r] * w12[r];
            sDel[l * 64 + dl] = softplus_f(acc);
        }
    }
    __syncthreads();

    // ---- serial scan: lane (g,q) covers d-pair {dl0, dl0+1}, n ∈ [4q,4q+4)
    int lane = tid & 63, wv = tid >> 6;   // wv in {0,1}
    int q = lane & 3;
    int g = lane >> 2;                    // [0,16)
    int dl0 = wv * 32 + g * 2;
    int d0 = dblk * 64 + dl0;
    int kd0 = k * DI + d0;
    int n0 = q << 2;

    float4 Aa = *(const float4*)(Alogs + (size_t)kd0 * NN + n0);
    float4 Ab = *(const float4*)(Alogs + (size_t)(kd0 + 1) * NN + n0);
    float A2a[4] = { -expf(Aa.x) * LOG2E, -expf(Aa.y) * LOG2E,
                     -expf(Aa.z) * LOG2E, -expf(Aa.w) * LOG2E };
    float A2b[4] = { -expf(Ab.x) * LOG2E, -expf(Ab.y) * LOG2E,
                     -expf(Ab.z) * LOG2E, -expf(Ab.w) * LOG2E };
    float Dva = Ds_g[kd0], Dvb = Ds_g[kd0 + 1];
    float* yc = yk   + ((size_t)bk * LL + l0 + q) * DI + d0;
    float* Sc = Sbuf + ((size_t)bk * LL + l0 + q) * DI + d0;

    float ha0 = 0.f, ha1 = 0.f, ha2 = 0.f, ha3 = 0.f;
    float hb0 = 0.f, hb1 = 0.f, hb2 = 0.f, hb3 = 0.f;
    float tda = 0.f, tdb = 0.f;
    float2 yhold = {0.f, 0.f}, Shold = {0.f, 0.f};

    #pragma unroll
    for (int l = 0; l < CLEN; ++l) {
        float2 del2 = *(const float2*)&sDel[l * 64 + dl0];
        float2 u2   = *(const float2*)&sU[l * 64 + dl0];
        tda += del2.x; tdb += del2.y;
        float dua = del2.x * u2.x;
        float dub = del2.y * u2.y;
        float4 B4 = *(const float4*)&sB[l * 16 + n0];
        ha0 = ha0 * fexp2(del2.x * A2a[0]) + dua * B4.x;
        ha1 = ha1 * fexp2(del2.x * A2a[1]) + dua * B4.y;
        ha2 = ha2 * fexp2(del2.x * A2a[2]) + dua * B4.z;
        ha3 = ha3 * fexp2(del2.x * A2a[3]) + dua * B4.w;
        hb0 = hb0 * fexp2(del2.y * A2b[0]) + dub * B4.x;
        hb1 = hb1 * fexp2(del2.y * A2b[1]) + dub * B4.y;
        hb2 = hb2 * fexp2(del2.y * A2b[2]) + dub * B4.z;
        hb3 = hb3 * fexp2(del2.y * A2b[3]) + dub * B4.w;
        float4 C4 = *(const float4*)&sC[l * 16 + n0];
        float ypa = ha0 * C4.x + ha1 * C4.y + ha2 * C4.z + ha3 * C4.w;
        float ypb = hb0 * C4.x + hb1 * C4.y + hb2 * C4.z + hb3 * C4.w;
        ypa += dpp_movf<0xB1>(ypa);
        ypa += dpp_movf<0x4E>(ypa);
        ypb += dpp_movf<0xB1>(ypb);
        ypb += dpp_movf<0x4E>(ypb);
        float yfa = ypa + u2.x * Dva;
        float yfb = ypb + u2.y * Dvb;
        if (q == (l & 3)) {
            yhold.x = yfa; yhold.y = yfb;
            Shold.x = tda; Shold.y = tdb;
        }
        if ((l & 3) == 3) {
            *(float2*)yc = yhold;
            *(float2*)Sc = Shold;
            yc += 4 * DI; Sc += 4 * DI;
        }
    }

    float4 h4a; h4a.x = ha0; h4a.y = ha1; h4a.z = ha2; h4a.w = ha3;
    float4 h4b; h4b.x = hb0; h4b.y = hb1; h4b.z = hb2; h4b.w = hb3;
    *(float4*)(hstin + ((size_t)(bk * CH + c) * DI + d0) * NN + n0) = h4a;
    *(float4*)(hstin + ((size_t)(bk * CH + c) * DI + d0 + 1) * NN + n0) = h4b;
}

// ---------------- combine (in-place): end-states -> incoming states
__global__ __launch_bounds__(256) void k_scan_combine(
    float* __restrict__ hstin,
    const float* __restrict__ Sbuf,
    const float* __restrict__ Alogs)
{
    int t = blockIdx.x * 256 + threadIdx.x;   // B*K*DI*NN = 98304
    int n = t & 15;
    int d = (t >> 4) % DI;
    int bk = t / (DI * NN);
    int k = bk & 3;
    float A2 = -expf(Alogs[(size_t)(k * DI + d) * NN + n]) * LOG2E;
    float h = 0.f;
    for (int c = 0; c < CH; ++c) {
        size_t rb = (size_t)(bk * CH + c) * DI + d;
        float hend = hstin[rb * NN + n];
        hstin[rb * NN + n] = h;
        float St = Sbuf[((size_t)bk * LL + c * CLEN + CLEN - 1) * DI + d];
        h = fexp2(A2 * St) * h + hend;
    }
}

// ---------------- correction: stage C,S in LDS, plain RMW on exclusive region
__global__ __launch_bounds__(256) void k_corr(
    const float* __restrict__ Csb,
    const float* __restrict__ Sbuf,
    const float* __restrict__ hin,
    const float* __restrict__ Alogs,
    float* __restrict__ yk)
{
    __shared__ float sC[CLEN * 16];      // [l][n]
    __shared__ float sS[CLEN * 64];      // [l][dl]

    int blk = blockIdx.x;                 // ((bk*CH + c)*6 + dblk)
    int dblk = blk % 6;
    int tmp = blk / 6;
    int c = tmp % CH;
    if (c == 0) return;
    int bk = tmp / CH;
    int k = bk & 3;
    int tid = threadIdx.x;
    int l0 = c * CLEN;

    {
        const float4* Cg = (const float4*)(Csb + ((size_t)bk * LL + l0) * NN);
        if (tid < CLEN * 4) ((float4*)sC)[tid] = Cg[tid];
        const float* Sg = Sbuf + ((size_t)bk * LL + l0) * DI + dblk * 64;
        #pragma unroll
        for (int it = 0; it < 3; ++it) {
            int i = it * 256 + tid;       // 768 float4
            int l = i >> 4, f4 = i & 15;
            ((float4*)sS)[l * 16 + f4] = *(const float4*)(Sg + (size_t)l * DI + f4 * 4);
        }
    }
    __syncthreads();

    int lane = tid & 63, wv = tid >> 6;
    int q = lane & 3;
    int d16 = lane >> 2;
    int dl = wv * 16 + d16;
    int d = dblk * 64 + dl;
    int kd = k * DI + d;
    int n0 = q << 2;

    float4 Al = *(const float4*)(Alogs + (size_t)kd * NN + n0);
    float A2[4] = { -expf(Al.x) * LOG2E, -expf(Al.y) * LOG2E,
                    -expf(Al.z) * LOG2E, -expf(Al.w) * LOG2E };
    float4 H4 = *(const float4*)(hin + ((size_t)(bk * CH + c) * DI + d) * NN + n0);
    float* yc = yk + ((size_t)bk * LL + l0 + q) * DI + d;

    float ychold = 0.f;
    #pragma unroll
    for (int l = 0; l < CLEN; ++l) {
        float S = sS[l * 64 + dl];
        float4 C4 = *(const float4*)&sC[l * 16 + n0];
        float yv = C4.x * fexp2(A2[0] * S) * H4.x
                 + C4.y * fexp2(A2[1] * S) * H4.y
                 + C4.z * fexp2(A2[2] * S) * H4.z
                 + C4.w * fexp2(A2[3] * S) * H4.w;
        yv += dpp_movf<0xB1>(yv);
        yv += dpp_movf<0x4E>(yv);
        if (q == (l & 3)) ychold = yv;
        if ((l & 3) == 3) {
            *yc += ychold;
            yc += 4 * DI;
        }
    }
}

// ---------------- merge (CrossMerge) + LayerNorm + gate -> bf16 gbuf
__global__ __launch_bounds__(384) void k_merge_ln_gate(
    const float* __restrict__ yk,
    const float* __restrict__ xcz,     // z at columns 384..767
    const float* __restrict__ lnw,
    const float* __restrict__ lnb,
    short* __restrict__ gbufb)
{
    int pg = blockIdx.x;            // b*LL + pos
    int b = pg / LL;
    int pos = pg % LL;
    int d = threadIdx.x;
    int pt = (pos % 48) * 48 + pos / 48;

    const float* y0 = yk + ((size_t)(b * 4 + 0) * LL + pos) * DI;
    const float* y1 = yk + ((size_t)(b * 4 + 1) * LL + pt) * DI;
    const float* y2 = yk + ((size_t)(b * 4 + 2) * LL + (LL - 1 - pos)) * DI;
    const float* y3 = yk + ((size_t)(b * 4 + 3) * LL + (LL - 1 - pt)) * DI;
    float v = y0[d] + y1[d] + y2[d] + y3[d];

    float s = v, qq = v * v;
    #pragma unroll
    for (int o = 32; o >= 1; o >>= 1) {
        s += __shfl_xor(s, o, 64);
        qq += __shfl_xor(qq, o, 64);
    }
    __shared__ float ssum[6], sqq[6];
    int lane = d & 63, w = d >> 6;
    if (lane == 0) { ssum[w] = s; sqq[w] = qq; }
    __syncthreads();
    float ts = 0.f, tq = 0.f;
    #pragma unroll
    for (int i = 0; i < 6; ++i) { ts += ssum[i]; tq += sqq[i]; }
    float mu = ts / (float)DI;
    float var = tq / (float)DI - mu * mu;
    float inv = rsqrtf(var + 1e-5f);
    float y = (v - mu) * inv * lnw[d] + lnb[d];
    float z = xcz[(size_t)pg * 768 + DI + d];
    gbufb[(size_t)pg * DI + d] = f2bf(y * z);
}

// ---------------- K6: out_proj via bf16 MFMA. K=384, tile 128l x 64o.
__global__ __launch_bounds__(256) void k_outproj_mfma(
    const short* __restrict__ gbufb,   // (B,L,384) bf16
    const short* __restrict__ owbf,    // (192,384) bf16
    float* __restrict__ out)           // (B,192,L) fp32
{
    __shared__ short sA[128 * 40];
    __shared__ short sB[64 * 40];
    int o0 = blockIdx.x * 64;
    int l0 = blockIdx.y * 128;
    int b  = blockIdx.z;
    int tid = threadIdx.x;
    int lane = tid & 63, wid = tid >> 6;
    int n = lane & 15, quad = lane >> 4;

    v4f acc[2][4];
    #pragma unroll
    for (int i = 0; i < 2; ++i)
        #pragma unroll
        for (int j = 0; j < 4; ++j) acc[i][j] = (v4f){0.f, 0.f, 0.f, 0.f};

    for (int kc = 0; kc < DI; kc += 32) {
        for (int i = tid; i < 512; i += 256) {
            int row = i >> 2, seg = i & 3;
            *(v8s*)&sA[row * 40 + seg * 8] =
                *(const v8s*)(gbufb + (size_t)(b * LL + l0 + row) * DI + kc + seg * 8);
        }
        {
            int row = tid >> 2, seg = tid & 3;
            *(v8s*)&sB[row * 40 + seg * 8] =
                *(const v8s*)(owbf + (size_t)(o0 + row) * DI + kc + seg * 8);
        }
        __syncthreads();
        v8s a0 = *(v8s*)&sA[(wid * 32 + n) * 40 + quad * 8];
        v8s a1 = *(v8s*)&sA[(wid * 32 + 16 + n) * 40 + quad * 8];
        #pragma unroll
        for (int os = 0; os < 4; ++os) {
            v8s bv = *(v8s*)&sB[(os * 16 + n) * 40 + quad * 8];
            acc[0][os] = __builtin_amdgcn_mfma_f32_16x16x32_bf16(a0, bv, acc[0][os], 0, 0, 0);
            acc[1][os] = __builtin_amdgcn_mfma_f32_16x16x32_bf16(a1, bv, acc[1][os], 0, 0, 0);
        }
        __syncthreads();
    }
    #pragma unroll
    for (int ls = 0; ls < 2; ++ls)
        #pragma unroll
        for (int os = 0; os < 4; ++os) {
            int o = o0 + os * 16 + n;
            #pragma unroll
            for (int r = 0; r < 4; ++r) {
                int l = l0 + wid * 32 + ls * 16 + quad * 4 + r;
                out[(size_t)(b * DM + o) * LL + l] = acc[ls][os][r];
            }
        }
}

extern "C" void kernel_launch(void* const* d_in, const int* in_sizes, int n_in,
                              void* d_out, int out_size, void* d_ws, size_t ws_size,
                              hipStream_t stream) {
    (void)in_sizes; (void)n_in; (void)out_size; (void)ws_size;
    const float* x      = (const float*)d_in[0];
    const float* ipw    = (const float*)d_in[1];
    const float* cw     = (const float*)d_in[2];
    const float* cb     = (const float*)d_in[3];
    const float* xpw    = (const float*)d_in[4];
    const float* dtw    = (const float*)d_in[5];
    const float* dtb    = (const float*)d_in[6];
    const float* Alogs  = (const float*)d_in[7];
    const float* Ds     = (const float*)d_in[8];
    const float* lnw    = (const float*)d_in[9];
    const float* lnb    = (const float*)d_in[10];
    const float* opw    = (const float*)d_in[11];
    float* out = (float*)d_out;

    float* wsf = (float*)d_ws;
    const size_t XCZ = (size_t)BQ * LL * 768;             //  7,077,888
    const size_t SZ  = (size_t)BQ * DI * LL;              //  3,538,944
    const size_t DTS = (size_t)BQ * KK * LL * RR;         //    442,368
    const size_t BCS = (size_t)BQ * KK * LL * NN;         //    589,824
    const size_t SBF = (size_t)BQ * KK * LL * DI;         // 14,155,776
    const size_t HST = (size_t)BQ * KK * CH * DI * NN;    //  4,718,592

    float* xcz   = wsf;                  // (B,L,768): xc half + gelu(z) half
    float* xcT   = xcz + XCZ;            // (B,L,384) fp32 conv output (scan u)
    float* dts   = xcT + SZ;             // (B,K,L,R)
    float* Bsb   = dts + DTS;            // (B,K,L,N)
    float* Csb   = Bsb + BCS;            // (B,K,L,N)
    float* Sbuf  = Csb + BCS;            // (B,K,L,DI)
    float* hstin = Sbuf + SBF;           // (B,K,CH,DI,N)
    float* yk    = hstin + HST;          // (B,K,L,DI)
    short* xTbf  = (short*)(yk + SBF);   // (B,L,192) bf16 in_proj input
    short* wibf  = xTbf + (size_t)BQ * LL * DM;   // (768,192)
    short* owbf  = wibf + 768 * 192;              // (192,384)
    short* wpbf  = owbf + 192 * 384;              // (192,384) x_proj padded
    // gbufb (B*L*384 shorts) aliases Sbuf: last reader k_corr finishes before
    // k_merge_ln_gate writes. xcTbf aliases yk (dead after k_xproj_mfma).
    short* gbufb = (short*)Sbuf;
    short* xcTbf = (short*)yk;

    k_prep_w<<<1152, 256, 0, stream>>>(ipw, opw, xpw, wibf, owbf, wpbf);
    k_prep_xT<<<BQ * 72 * 6, 256, 0, stream>>>(x, xTbf);
    k_inproj_mfma<<<dim3(12, 18, BQ), 256, 0, stream>>>(xTbf, wibf, xcz);
    k_dwconv<<<BQ * HH * 4, 384, 0, stream>>>(xcz, cw, cb, xcT, xcTbf);
    k_xproj_mfma<<<dim3(3, 18, BQ), 256, 0, stream>>>(xcTbf, wpbf, dts, Bsb, Csb);

    k_scan_pass1<<<BQ * KK * CH * 6, 128, 0, stream>>>(
        xcT, dts, Bsb, Csb, dtw, dtb, Alogs, Ds, Sbuf, hstin, yk);
    k_scan_combine<<<(BQ * KK * DI * NN) / 256, 256, 0, stream>>>(
        hstin, Sbuf, Alogs);
    k_corr<<<BQ * KK * CH * 6, 256, 0, stream>>>(Csb, Sbuf, hstin, Alogs, yk);
    k_merge_ln_gate<<<BQ * LL, 384, 0, stream>>>(yk, xcz, lnw, lnb, gbufb);

    k_outproj_mfma<<<dim3(3, 18, BQ), 256, 0, stream>>>(gbufb, owbf, out);
}

// Round 15
// 305.800 us; speedup vs baseline: 1.3710x; 1.3710x over previous
//
#include <hip/hip_runtime.h>
#include <math.h>

#define BQ 4
#define DM 192
#define DI 384
#define HH 48
#define WW 48
#define LL 2304
#define KK 4
#define NN 16
#define RR 12
#define CH 48      // chunks per sequence
#define CLEN 48    // chunk length

#define LOG2E 1.4426950408889634f

typedef short v8s __attribute__((ext_vector_type(8)));
typedef float v4f __attribute__((ext_vector_type(4)));

__device__ __forceinline__ float gelu_exact(float x) {
    return 0.5f * x * (1.0f + erff(x * 0.7071067811865476f));
}

__device__ __forceinline__ float softplus_f(float x) {
    return fmaxf(x, 0.0f) + log1pf(expf(-fabsf(x)));
}

__device__ __forceinline__ int pos_for(int k, int l) {
    if (k == 0) return l;
    if (k == 1) { return (l % HH) * WW + (l / HH); }
    if (k == 2) return (LL - 1) - l;
    int j = (LL - 1) - l;
    return (j % HH) * WW + (j / HH);
}

__device__ __forceinline__ int pt_of(int p) {   // 48x48 transpose, involution
    return (p % 48) * 48 + p / 48;
}

__device__ __forceinline__ float fexp2(float x) {
    return __builtin_amdgcn_exp2f(x);
}

__device__ __forceinline__ short f2bf(float x) {
    unsigned u = __float_as_uint(x);
    unsigned r = (u + 0x7FFFu + ((u >> 16) & 1u)) >> 16;
    return (short)r;
}

// DPP move: 0x00-0xFF quad_perm; 0xB1 = quad xor1, 0x4E = quad xor2.
template<int CTRL>
__device__ __forceinline__ float dpp_movf(float v) {
    return __int_as_float(__builtin_amdgcn_update_dpp(
        0, __float_as_int(v), CTRL, 0xF, 0xF, true));
}

// ---------------- P1: cast weights to bf16. wpbf = x_proj (176,384) padded to 192 rows.
__global__ __launch_bounds__(256) void k_prep_w(const float* __restrict__ ipw,
                                                const float* __restrict__ opw,
                                                const float* __restrict__ xpw,
                                                short* __restrict__ wibf,
                                                short* __restrict__ owbf,
                                                short* __restrict__ wpbf) {
    int i = blockIdx.x * 256 + threadIdx.x;     // 1152*256 = 294912 exactly
    if (i < 147456)       wibf[i] = f2bf(ipw[i]);
    else if (i < 221184)  owbf[i - 147456] = f2bf(opw[i - 147456]);
    else if (i < 288768)  wpbf[i - 221184] = f2bf(xpw[i - 221184]);
    else                  wpbf[67584 + (i - 288768)] = 0;   // pad rows 176..191
}

// ---------------- P2: transpose-cast x (B,192,L) -> xTbf (B,L,192) bf16
__global__ __launch_bounds__(256) void k_prep_xT(const float* __restrict__ x,
                                                 short* __restrict__ xTbf) {
    __shared__ float T[32][33];
    int blk = blockIdx.x;           // (b*72 + lt)*6 + dt
    int dt = blk % 6;
    int lt = (blk / 6) % 72;
    int b  = blk / (6 * 72);
    int d0 = dt * 32, l0 = lt * 32;
    int tx = threadIdx.x & 31, ty = threadIdx.x >> 5;   // ty 0..7
    #pragma unroll
    for (int i = 0; i < 4; ++i) {
        int dd = ty + 8 * i;
        T[dd][tx] = x[(size_t)(b * DM + d0 + dd) * LL + l0 + tx];
    }
    __syncthreads();
    #pragma unroll
    for (int i = 0; i < 4; ++i) {
        int ll = ty + 8 * i;
        xTbf[(size_t)(b * LL + l0 + ll) * DM + d0 + tx] = f2bf(T[tx][ll]);
    }
}

// ---------------- K1: in_proj via bf16 MFMA. D[l][o]; o<384 -> xc, else gelu->z.
__global__ __launch_bounds__(256) void k_inproj_mfma(
    const short* __restrict__ xTbf,   // (B,L,192) bf16
    const short* __restrict__ wibf,   // (768,192) bf16
    float* __restrict__ xcz)          // (B,L,768) fp32
{
    __shared__ short sA[128 * 40];    // [l][k32], row stride 40 shorts
    __shared__ short sB[64 * 40];     // [o][k32]
    int o0 = blockIdx.x * 64;
    int l0 = blockIdx.y * 128;
    int b  = blockIdx.z;
    int tid = threadIdx.x;
    int lane = tid & 63, wid = tid >> 6;
    int n = lane & 15, quad = lane >> 4;

    v4f acc[2][4];
    #pragma unroll
    for (int i = 0; i < 2; ++i)
        #pragma unroll
        for (int j = 0; j < 4; ++j) acc[i][j] = (v4f){0.f, 0.f, 0.f, 0.f};

    for (int kc = 0; kc < 192; kc += 32) {
        for (int i = tid; i < 512; i += 256) {
            int row = i >> 2, seg = i & 3;
            *(v8s*)&sA[row * 40 + seg * 8] =
                *(const v8s*)(xTbf + (size_t)(b * LL + l0 + row) * DM + kc + seg * 8);
        }
        {
            int row = tid >> 2, seg = tid & 3;
            *(v8s*)&sB[row * 40 + seg * 8] =
                *(const v8s*)(wibf + (size_t)(o0 + row) * DM + kc + seg * 8);
        }
        __syncthreads();
        v8s a0 = *(v8s*)&sA[(wid * 32 + n) * 40 + quad * 8];
        v8s a1 = *(v8s*)&sA[(wid * 32 + 16 + n) * 40 + quad * 8];
        #pragma unroll
        for (int os = 0; os < 4; ++os) {
            v8s bv = *(v8s*)&sB[(os * 16 + n) * 40 + quad * 8];
            acc[0][os] = __builtin_amdgcn_mfma_f32_16x16x32_bf16(a0, bv, acc[0][os], 0, 0, 0);
            acc[1][os] = __builtin_amdgcn_mfma_f32_16x16x32_bf16(a1, bv, acc[1][os], 0, 0, 0);
        }
        __syncthreads();
    }
    bool zhalf = (o0 >= DI);
    #pragma unroll
    for (int ls = 0; ls < 2; ++ls)
        #pragma unroll
        for (int os = 0; os < 4; ++os) {
            int o = o0 + os * 16 + n;
            #pragma unroll
            for (int r = 0; r < 4; ++r) {
                int l = l0 + wid * 32 + ls * 16 + quad * 4 + r;
                float v = acc[ls][os][r];
                xcz[(size_t)(b * LL + l) * 768 + o] = zhalf ? gelu_exact(v) : v;
            }
        }
}

// ---------------- K2: depthwise 3x3 conv + bias + gelu, [l][c] layout.
__global__ __launch_bounds__(384) void k_dwconv(const float* __restrict__ xcz,
                                                const float* __restrict__ cw,
                                                const float* __restrict__ cb,
                                                float* __restrict__ xcT,
                                                short* __restrict__ xcTbf) {
    int blk = blockIdx.x;           // ((b*HH + h)*4 + seg)
    int seg = blk & 3;
    int bh = blk >> 2;
    int b = bh / HH, h = bh % HH;
    int d = threadIdx.x;
    int w0 = seg * 12;
    const float* in = xcz + (size_t)b * LL * 768 + d;
    float w9[9];
    #pragma unroll
    for (int i = 0; i < 9; ++i) w9[i] = cw[d * 9 + i];
    float bias = cb[d];
    bool hm = h > 0, hp = h < HH - 1;
    int r0 = (h - 1) * WW, r1 = h * WW, r2 = (h + 1) * WW;
    float c00, c01, c02, c10, c11, c12, c20, c21, c22;
    bool wl = (w0 > 0);
    c00 = (hm && wl) ? in[(size_t)(r0 + w0 - 1) * 768] : 0.f;
    c10 = wl ? in[(size_t)(r1 + w0 - 1) * 768] : 0.f;
    c20 = (hp && wl) ? in[(size_t)(r2 + w0 - 1) * 768] : 0.f;
    c01 = hm ? in[(size_t)(r0 + w0) * 768] : 0.f;
    c11 = in[(size_t)(r1 + w0) * 768];
    c21 = hp ? in[(size_t)(r2 + w0) * 768] : 0.f;
    c02 = hm ? in[(size_t)(r0 + w0 + 1) * 768] : 0.f;
    c12 = in[(size_t)(r1 + w0 + 1) * 768];
    c22 = hp ? in[(size_t)(r2 + w0 + 1) * 768] : 0.f;
    #pragma unroll
    for (int wi = 0; wi < 12; ++wi) {
        int w = w0 + wi;
        float s = bias
            + w9[0] * c00 + w9[1] * c01 + w9[2] * c02
            + w9[3] * c10 + w9[4] * c11 + w9[5] * c12
            + w9[6] * c20 + w9[7] * c21 + w9[8] * c22;
        float v = gelu_exact(s);
        size_t row = (size_t)(b * LL + h * WW + w);
        xcT[row * DI + d] = v;
        xcTbf[row * DI + d] = f2bf(v);
        c00 = c01; c01 = c02; c10 = c11; c11 = c12; c20 = c21; c21 = c22;
        int wn = w + 2;
        bool okw = wn < WW;
        c02 = (hm && okw) ? in[(size_t)(r0 + wn) * 768] : 0.f;
        c12 = okw ? in[(size_t)(r1 + wn) * 768] : 0.f;
        c22 = (hp && okw) ? in[(size_t)(r2 + wn) * 768] : 0.f;
    }
}

// ---------------- K3: x_proj, ALL 4 directions as ONE bf16 MFMA GEMM.
__global__ __launch_bounds__(256) void k_xproj_mfma(
    const short* __restrict__ xcTbf,  // (B,L,384) bf16
    const short* __restrict__ wpbf,   // (192,384) bf16, rows>=176 zero
    float* __restrict__ dts,
    float* __restrict__ Bsb,
    float* __restrict__ Csb)
{
    __shared__ short sA[128 * 40];
    __shared__ short sB[64 * 40];
    int o0 = blockIdx.x * 64;
    int l0 = blockIdx.y * 128;
    int b  = blockIdx.z;
    int tid = threadIdx.x;
    int lane = tid & 63, wid = tid >> 6;
    int n = lane & 15, quad = lane >> 4;

    v4f acc[2][4];
    #pragma unroll
    for (int i = 0; i < 2; ++i)
        #pragma unroll
        for (int j = 0; j < 4; ++j) acc[i][j] = (v4f){0.f, 0.f, 0.f, 0.f};

    for (int kc = 0; kc < DI; kc += 32) {
        for (int i = tid; i < 512; i += 256) {
            int row = i >> 2, seg = i & 3;
            *(v8s*)&sA[row * 40 + seg * 8] =
                *(const v8s*)(xcTbf + (size_t)(b * LL + l0 + row) * DI + kc + seg * 8);
        }
        {
            int row = tid >> 2, seg = tid & 3;
            *(v8s*)&sB[row * 40 + seg * 8] =
                *(const v8s*)(wpbf + (size_t)(o0 + row) * DI + kc + seg * 8);
        }
        __syncthreads();
        v8s a0 = *(v8s*)&sA[(wid * 32 + n) * 40 + quad * 8];
        v8s a1 = *(v8s*)&sA[(wid * 32 + 16 + n) * 40 + quad * 8];
        #pragma unroll
        for (int os = 0; os < 4; ++os) {
            v8s bv = *(v8s*)&sB[(os * 16 + n) * 40 + quad * 8];
            acc[0][os] = __builtin_amdgcn_mfma_f32_16x16x32_bf16(a0, bv, acc[0][os], 0, 0, 0);
            acc[1][os] = __builtin_amdgcn_mfma_f32_16x16x32_bf16(a1, bv, acc[1][os], 0, 0, 0);
        }
        __syncthreads();
    }
    #pragma unroll
    for (int ls = 0; ls < 2; ++ls)
        #pragma unroll
        for (int os = 0; os < 4; ++os) {
            int c_all = o0 + os * 16 + n;
            if (c_all >= 176) continue;
            int k = c_all / 44;
            int c = c_all - k * 44;
            int bk = b * 4 + k;
            #pragma unroll
            for (int r = 0; r < 4; ++r) {
                int lp = l0 + wid * 32 + ls * 16 + quad * 4 + r;
                int lk = (k == 0) ? lp
                       : (k == 1) ? pt_of(lp)
                       : (k == 2) ? (LL - 1 - lp)
                                  : (LL - 1 - pt_of(lp));
                float v = acc[ls][os][r];
                size_t base = (size_t)bk * LL + lk;
                if (c < RR)           dts[base * RR + c] = v;
                else if (c < RR + NN) Bsb[base * NN + (c - RR)] = v;
                else                  Csb[base * NN + (c - RR - NN)] = v;
            }
        }
}

// ---------------- Single-pass chunked scan, stage-then-scan (R11 config:
// 256 threads, 16 d/wave — measured local optimum; R12-R14 perturbations
// of chunk geometry / lane layout / S-stream all regressed).
__global__ __launch_bounds__(256) void k_scan_pass1(
    const float* __restrict__ xcT,
    const float* __restrict__ dts,
    const float* __restrict__ Bsb,
    const float* __restrict__ Csb,
    const float* __restrict__ dtw_g,
    const float* __restrict__ dtb_g,
    const float* __restrict__ Alogs,
    const float* __restrict__ Ds_g,
    float* __restrict__ Sbuf,
    float* __restrict__ hstin,
    float* __restrict__ yk)
{
    __shared__ float sB[CLEN * 16];      // [l][n]
    __shared__ float sC[CLEN * 16];
    __shared__ float sDts[CLEN * 12];    // [l][r]
    __shared__ float sDel[CLEN * 64];    // [l][dl]
    __shared__ float sU[CLEN * 64];      // [l][dl]

    int blk = blockIdx.x;                 // ((bk*CH + c)*6 + dblk)
    int dblk = blk % 6;
    int tmp = blk / 6;
    int c = tmp % CH;
    int bk = tmp / CH;
    int k = bk & 3, b = bk >> 2;
    int tid = threadIdx.x;
    int l0 = c * CLEN;

    {
        const float4* Bg = (const float4*)(Bsb + ((size_t)bk * LL + l0) * NN);
        const float4* Cg = (const float4*)(Csb + ((size_t)bk * LL + l0) * NN);
        if (tid < CLEN * 4) {
            ((float4*)sB)[tid] = Bg[tid];
            ((float4*)sC)[tid] = Cg[tid];
        }
        const float4* Dg = (const float4*)(dts + ((size_t)bk * LL + l0) * RR);
        for (int i = tid; i < CLEN * 3; i += 256)
            ((float4*)sDts)[i] = Dg[i];
    }
    {
        const float* xb = xcT + (size_t)b * LL * DI + dblk * 64;
        #pragma unroll
        for (int it = 0; it < 3; ++it) {
            int i = it * 256 + tid;       // 768 float4
            int l = i >> 4, f4 = i & 15;
            int pos = pos_for(k, l0 + l);
            ((float4*)sU)[l * 16 + f4] = *(const float4*)(xb + (size_t)pos * DI + f4 * 4);
        }
    }
    __syncthreads();
    {
        int dl = tid & 63, lset = tid >> 6;
        int dd = dblk * 64 + dl;
        int kdq = k * DI + dd;
        float dtbv = dtb_g[kdq];
        float w12[12];
        {
            const float4* p = (const float4*)(dtw_g + (size_t)kdq * RR);
            float4 a0 = p[0], a1 = p[1], a2 = p[2];
            w12[0]=a0.x; w12[1]=a0.y; w12[2]=a0.z;  w12[3]=a0.w;
            w12[4]=a1.x; w12[5]=a1.y; w12[6]=a1.z;  w12[7]=a1.w;
            w12[8]=a2.x; w12[9]=a2.y; w12[10]=a2.z; w12[11]=a2.w;
        }
        #pragma unroll
        for (int j = 0; j < 12; ++j) {
            int l = lset * 12 + j;
            const float* dp = sDts + l * 12;
            float acc = dtbv;
            #pragma unroll
            for (int r = 0; r < 12; ++r) acc += dp[r] * w12[r];
            sDel[l * 64 + dl] = softplus_f(acc);
        }
    }
    __syncthreads();

    int lane = tid & 63, wv = tid >> 6;
    int q = lane & 3;
    int d16 = lane >> 2;
    int dl = wv * 16 + d16;
    int d = dblk * 64 + dl;
    int kd = k * DI + d;
    int n0 = q << 2;

    float4 Al = *(const float4*)(Alogs + (size_t)kd * NN + n0);
    float A2[4] = { -expf(Al.x) * LOG2E, -expf(Al.y) * LOG2E,
                    -expf(Al.z) * LOG2E, -expf(Al.w) * LOG2E };
    float Dv = Ds_g[kd];
    float* Sc = Sbuf + ((size_t)bk * LL + l0 + q) * DI + d;
    float* yc = yk   + ((size_t)bk * LL + l0 + q) * DI + d;

    float h0 = 0.f, h1 = 0.f, h2 = 0.f, h3 = 0.f;
    float td = 0.f;
    float yhold = 0.f, Shold = 0.f;

    #pragma unroll
    for (int l = 0; l < CLEN; ++l) {
        float delta = sDel[l * 64 + dl];
        float ub_b  = sU[l * 64 + dl];
        td += delta;
        float du = delta * ub_b;
        float4 B4 = *(const float4*)&sB[l * 16 + n0];
        h0 = h0 * fexp2(delta * A2[0]) + du * B4.x;
        h1 = h1 * fexp2(delta * A2[1]) + du * B4.y;
        h2 = h2 * fexp2(delta * A2[2]) + du * B4.z;
        h3 = h3 * fexp2(delta * A2[3]) + du * B4.w;
        float4 C4 = *(const float4*)&sC[l * 16 + n0];
        float yp = h0 * C4.x + h1 * C4.y + h2 * C4.z + h3 * C4.w;
        yp += dpp_movf<0xB1>(yp);
        yp += dpp_movf<0x4E>(yp);
        float yf = yp + ub_b * Dv;
        if (q == (l & 3)) { yhold = yf; Shold = td; }
        if ((l & 3) == 3) {
            *yc = yhold; *Sc = Shold;
            yc += 4 * DI; Sc += 4 * DI;
        }
    }

    float4 h4; h4.x = h0; h4.y = h1; h4.z = h2; h4.w = h3;
    *(float4*)(hstin + ((size_t)(bk * CH + c) * DI + d) * NN + n0) = h4;
}

// ---------------- combine (in-place): end-states -> incoming states
__global__ __launch_bounds__(256) void k_scan_combine(
    float* __restrict__ hstin,
    const float* __restrict__ Sbuf,
    const float* __restrict__ Alogs)
{
    int t = blockIdx.x * 256 + threadIdx.x;   // B*K*DI*NN = 98304
    int n = t & 15;
    int d = (t >> 4) % DI;
    int bk = t / (DI * NN);
    int k = bk & 3;
    float A2 = -expf(Alogs[(size_t)(k * DI + d) * NN + n]) * LOG2E;
    float h = 0.f;
    for (int c = 0; c < CH; ++c) {
        size_t rb = (size_t)(bk * CH + c) * DI + d;
        float hend = hstin[rb * NN + n];
        hstin[rb * NN + n] = h;
        float St = Sbuf[((size_t)bk * LL + c * CLEN + CLEN - 1) * DI + d];
        h = fexp2(A2 * St) * h + hend;
    }
}

// ---------------- correction: stage C,S in LDS, plain RMW on exclusive region
__global__ __launch_bounds__(256) void k_corr(
    const float* __restrict__ Csb,
    const float* __restrict__ Sbuf,
    const float* __restrict__ hin,
    const float* __restrict__ Alogs,
    float* __restrict__ yk)
{
    __shared__ float sC[CLEN * 16];      // [l][n]
    __shared__ float sS[CLEN * 64];      // [l][dl]

    int blk = blockIdx.x;                 // ((bk*CH + c)*6 + dblk)
    int dblk = blk % 6;
    int tmp = blk / 6;
    int c = tmp % CH;
    if (c == 0) return;
    int bk = tmp / CH;
    int k = bk & 3;
    int tid = threadIdx.x;
    int l0 = c * CLEN;

    {
        const float4* Cg = (const float4*)(Csb + ((size_t)bk * LL + l0) * NN);
        if (tid < CLEN * 4) ((float4*)sC)[tid] = Cg[tid];
        const float* Sg = Sbuf + ((size_t)bk * LL + l0) * DI + dblk * 64;
        #pragma unroll
        for (int it = 0; it < 3; ++it) {
            int i = it * 256 + tid;       // 768 float4
            int l = i >> 4, f4 = i & 15;
            ((float4*)sS)[l * 16 + f4] = *(const float4*)(Sg + (size_t)l * DI + f4 * 4);
        }
    }
    __syncthreads();

    int lane = tid & 63, wv = tid >> 6;
    int q = lane & 3;
    int d16 = lane >> 2;
    int dl = wv * 16 + d16;
    int d = dblk * 64 + dl;
    int kd = k * DI + d;
    int n0 = q << 2;

    float4 Al = *(const float4*)(Alogs + (size_t)kd * NN + n0);
    float A2[4] = { -expf(Al.x) * LOG2E, -expf(Al.y) * LOG2E,
                    -expf(Al.z) * LOG2E, -expf(Al.w) * LOG2E };
    float4 H4 = *(const float4*)(hin + ((size_t)(bk * CH + c) * DI + d) * NN + n0);
    float* yc = yk + ((size_t)bk * LL + l0 + q) * DI + d;

    float ychold = 0.f;
    #pragma unroll
    for (int l = 0; l < CLEN; ++l) {
        float S = sS[l * 64 + dl];
        float4 C4 = *(const float4*)&sC[l * 16 + n0];
        float yv = C4.x * fexp2(A2[0] * S) * H4.x
                 + C4.y * fexp2(A2[1] * S) * H4.y
                 + C4.z * fexp2(A2[2] * S) * H4.z
                 + C4.w * fexp2(A2[3] * S) * H4.w;
        yv += dpp_movf<0xB1>(yv);
        yv += dpp_movf<0x4E>(yv);
        if (q == (l & 3)) ychold = yv;
        if ((l & 3) == 3) {
            *yc += ychold;
            yc += 4 * DI;
        }
    }
}

// ---------------- merge (CrossMerge) + LayerNorm + gate -> bf16 gbuf
__global__ __launch_bounds__(384) void k_merge_ln_gate(
    const float* __restrict__ yk,
    const float* __restrict__ xcz,     // z at columns 384..767
    const float* __restrict__ lnw,
    const float* __restrict__ lnb,
    short* __restrict__ gbufb)
{
    int pg = blockIdx.x;            // b*LL + pos
    int b = pg / LL;
    int pos = pg % LL;
    int d = threadIdx.x;
    int pt = (pos % 48) * 48 + pos / 48;

    const float* y0 = yk + ((size_t)(b * 4 + 0) * LL + pos) * DI;
    const float* y1 = yk + ((size_t)(b * 4 + 1) * LL + pt) * DI;
    const float* y2 = yk + ((size_t)(b * 4 + 2) * LL + (LL - 1 - pos)) * DI;
    const float* y3 = yk + ((size_t)(b * 4 + 3) * LL + (LL - 1 - pt)) * DI;
    float v = y0[d] + y1[d] + y2[d] + y3[d];

    float s = v, qq = v * v;
    #pragma unroll
    for (int o = 32; o >= 1; o >>= 1) {
        s += __shfl_xor(s, o, 64);
        qq += __shfl_xor(qq, o, 64);
    }
    __shared__ float ssum[6], sqq[6];
    int lane = d & 63, w = d >> 6;
    if (lane == 0) { ssum[w] = s; sqq[w] = qq; }
    __syncthreads();
    float ts = 0.f, tq = 0.f;
    #pragma unroll
    for (int i = 0; i < 6; ++i) { ts += ssum[i]; tq += sqq[i]; }
    float mu = ts / (float)DI;
    float var = tq / (float)DI - mu * mu;
    float inv = rsqrtf(var + 1e-5f);
    float y = (v - mu) * inv * lnw[d] + lnb[d];
    float z = xcz[(size_t)pg * 768 + DI + d];
    gbufb[(size_t)pg * DI + d] = f2bf(y * z);
}

// ---------------- K6: out_proj via bf16 MFMA. K=384, tile 128l x 64o.
__global__ __launch_bounds__(256) void k_outproj_mfma(
    const short* __restrict__ gbufb,   // (B,L,384) bf16
    const short* __restrict__ owbf,    // (192,384) bf16
    float* __restrict__ out)           // (B,192,L) fp32
{
    __shared__ short sA[128 * 40];
    __shared__ short sB[64 * 40];
    int o0 = blockIdx.x * 64;
    int l0 = blockIdx.y * 128;
    int b  = blockIdx.z;
    int tid = threadIdx.x;
    int lane = tid & 63, wid = tid >> 6;
    int n = lane & 15, quad = lane >> 4;

    v4f acc[2][4];
    #pragma unroll
    for (int i = 0; i < 2; ++i)
        #pragma unroll
        for (int j = 0; j < 4; ++j) acc[i][j] = (v4f){0.f, 0.f, 0.f, 0.f};

    for (int kc = 0; kc < DI; kc += 32) {
        for (int i = tid; i < 512; i += 256) {
            int row = i >> 2, seg = i & 3;
            *(v8s*)&sA[row * 40 + seg * 8] =
                *(const v8s*)(gbufb + (size_t)(b * LL + l0 + row) * DI + kc + seg * 8);
        }
        {
            int row = tid >> 2, seg = tid & 3;
            *(v8s*)&sB[row * 40 + seg * 8] =
                *(const v8s*)(owbf + (size_t)(o0 + row) * DI + kc + seg * 8);
        }
        __syncthreads();
        v8s a0 = *(v8s*)&sA[(wid * 32 + n) * 40 + quad * 8];
        v8s a1 = *(v8s*)&sA[(wid * 32 + 16 + n) * 40 + quad * 8];
        #pragma unroll
        for (int os = 0; os < 4; ++os) {
            v8s bv = *(v8s*)&sB[(os * 16 + n) * 40 + quad * 8];
            acc[0][os] = __builtin_amdgcn_mfma_f32_16x16x32_bf16(a0, bv, acc[0][os], 0, 0, 0);
            acc[1][os] = __builtin_amdgcn_mfma_f32_16x16x32_bf16(a1, bv, acc[1][os], 0, 0, 0);
        }
        __syncthreads();
    }
    #pragma unroll
    for (int ls = 0; ls < 2; ++ls)
        #pragma unroll
        for (int os = 0; os < 4; ++os) {
            int o = o0 + os * 16 + n;
            #pragma unroll
            for (int r = 0; r < 4; ++r) {
                int l = l0 + wid * 32 + ls * 16 + quad * 4 + r;
                out[(size_t)(b * DM + o) * LL + l] = acc[ls][os][r];
            }
        }
}

extern "C" void kernel_launch(void* const* d_in, const int* in_sizes, int n_in,
                              void* d_out, int out_size, void* d_ws, size_t ws_size,
                              hipStream_t stream) {
    (void)in_sizes; (void)n_in; (void)out_size; (void)ws_size;
    const float* x      = (const float*)d_in[0];
    const float* ipw    = (const float*)d_in[1];
    const float* cw     = (const float*)d_in[2];
    const float* cb     = (const float*)d_in[3];
    const float* xpw    = (const float*)d_in[4];
    const float* dtw    = (const float*)d_in[5];
    const float* dtb    = (const float*)d_in[6];
    const float* Alogs  = (const float*)d_in[7];
    const float* Ds     = (const float*)d_in[8];
    const float* lnw    = (const float*)d_in[9];
    const float* lnb    = (const float*)d_in[10];
    const float* opw    = (const float*)d_in[11];
    float* out = (float*)d_out;

    float* wsf = (float*)d_ws;
    const size_t XCZ = (size_t)BQ * LL * 768;             //  7,077,888
    const size_t SZ  = (size_t)BQ * DI * LL;              //  3,538,944
    const size_t DTS = (size_t)BQ * KK * LL * RR;         //    442,368
    const size_t BCS = (size_t)BQ * KK * LL * NN;         //    589,824
    const size_t SBF = (size_t)BQ * KK * LL * DI;         // 14,155,776
    const size_t HST = (size_t)BQ * KK * CH * DI * NN;    //  4,718,592

    float* xcz   = wsf;                  // (B,L,768): xc half + gelu(z) half
    float* xcT   = xcz + XCZ;            // (B,L,384) fp32 conv output (scan u)
    float* dts   = xcT + SZ;             // (B,K,L,R)
    float* Bsb   = dts + DTS;            // (B,K,L,N)
    float* Csb   = Bsb + BCS;            // (B,K,L,N)
    float* Sbuf  = Csb + BCS;            // (B,K,L,DI)
    float* hstin = Sbuf + SBF;           // (B,K,CH,DI,N)
    float* yk    = hstin + HST;          // (B,K,L,DI)
    short* xTbf  = (short*)(yk + SBF);   // (B,L,192) bf16 in_proj input
    short* wibf  = xTbf + (size_t)BQ * LL * DM;   // (768,192)
    short* owbf  = wibf + 768 * 192;              // (192,384)
    short* wpbf  = owbf + 192 * 384;              // (192,384) x_proj padded
    // gbufb (B*L*384 shorts) aliases Sbuf: last reader k_corr finishes before
    // k_merge_ln_gate writes. xcTbf aliases yk (dead after k_xproj_mfma).
    short* gbufb = (short*)Sbuf;
    short* xcTbf = (short*)yk;

    k_prep_w<<<1152, 256, 0, stream>>>(ipw, opw, xpw, wibf, owbf, wpbf);
    k_prep_xT<<<BQ * 72 * 6, 256, 0, stream>>>(x, xTbf);
    k_inproj_mfma<<<dim3(12, 18, BQ), 256, 0, stream>>>(xTbf, wibf, xcz);
    k_dwconv<<<BQ * HH * 4, 384, 0, stream>>>(xcz, cw, cb, xcT, xcTbf);
    k_xproj_mfma<<<dim3(3, 18, BQ), 256, 0, stream>>>(xcTbf, wpbf, dts, Bsb, Csb);

    k_scan_pass1<<<BQ * KK * CH * 6, 256, 0, stream>>>(
        xcT, dts, Bsb, Csb, dtw, dtb, Alogs, Ds, Sbuf, hstin, yk);
    k_scan_combine<<<(BQ * KK * DI * NN) / 256, 256, 0, stream>>>(
        hstin, Sbuf, Alogs);
    k_corr<<<BQ * KK * CH * 6, 256, 0, stream>>>(Csb, Sbuf, hstin, Alogs, yk);
    k_merge_ln_gate<<<BQ * LL, 384, 0, stream>>>(yk, xcz, lnw, lnb, gbufb);

    k_outproj_mfma<<<dim3(3, 18, BQ), 256, 0, stream>>>(gbufb, owbf, out);
}